// Round 1
// baseline (33.598 us; speedup 1.0000x reference)
//
#include <hip/hip_runtime.h>
#include <math.h>

#define NB 64
#define NS 512
#define NH 768
#define NT 3
#define EMIS_N (NB * NS * NT)   // 98304
#define NEGINF (-1e30f)

__device__ __forceinline__ float lse3(float a, float b, float c) {
    float m = fmaxf(fmaxf(a, b), c);
    return m + __logf(__expf(a - m) + __expf(b - m) + __expf(c - m));
}

// ---------------------------------------------------------------------------
// Kernel 1: emissions = relu(hidden @ W + b). One wave per (b,s) row,
// 4 rows per wave (grid 2048x256 = 8192 waves, 32768 rows).
// Memory-bound: streams 96 MB of hidden.
// ---------------------------------------------------------------------------
__global__ __launch_bounds__(256) void emis_kernel(
    const float* __restrict__ hidden,   // [NB*NS, NH]
    const float* __restrict__ W,        // [NH, NT]
    const float* __restrict__ bias,     // [NT]
    float* __restrict__ out)            // d_out: emissions [NB*NS, NT], then nll
{
    if (blockIdx.x == 0 && threadIdx.x == 0) out[EMIS_N] = 0.0f;  // init nll acc

    const int lane = threadIdx.x & 63;
    const int wid  = blockIdx.x * 4 + (threadIdx.x >> 6);   // 0..8191

    // Per-lane W slice: for it in 0..2, h = it*256 + lane*4 + k (k=0..3)
    // w[it][k*3+t] = W[h][t] -> 12 consecutive floats = 3 float4 loads.
    float w[3][12];
    #pragma unroll
    for (int it = 0; it < 3; ++it) {
        const float4* wp = reinterpret_cast<const float4*>(W + (it * 256 + lane * 4) * NT);
        float4 q0 = wp[0], q1 = wp[1], q2 = wp[2];
        w[it][0] = q0.x; w[it][1]  = q0.y; w[it][2]  = q0.z; w[it][3]  = q0.w;
        w[it][4] = q1.x; w[it][5]  = q1.y; w[it][6]  = q1.z; w[it][7]  = q1.w;
        w[it][8] = q2.x; w[it][9]  = q2.y; w[it][10] = q2.z; w[it][11] = q2.w;
    }
    const float b0 = bias[0], b1 = bias[1], b2 = bias[2];

    #pragma unroll
    for (int r = 0; r < 4; ++r) {
        const int row = wid + r * 8192;
        const float4* hp = reinterpret_cast<const float4*>(hidden + (size_t)row * NH);
        float a0 = 0.f, a1 = 0.f, a2 = 0.f;
        #pragma unroll
        for (int it = 0; it < 3; ++it) {
            float4 x = hp[it * 64 + lane];
            const float* wt = w[it];
            a0 = fmaf(x.x, wt[0], a0); a1 = fmaf(x.x, wt[1],  a1); a2 = fmaf(x.x, wt[2],  a2);
            a0 = fmaf(x.y, wt[3], a0); a1 = fmaf(x.y, wt[4],  a1); a2 = fmaf(x.y, wt[5],  a2);
            a0 = fmaf(x.z, wt[6], a0); a1 = fmaf(x.z, wt[7],  a1); a2 = fmaf(x.z, wt[8],  a2);
            a0 = fmaf(x.w, wt[9], a0); a1 = fmaf(x.w, wt[10], a1); a2 = fmaf(x.w, wt[11], a2);
        }
        #pragma unroll
        for (int d = 32; d; d >>= 1) {
            a0 += __shfl_xor(a0, d);
            a1 += __shfl_xor(a1, d);
            a2 += __shfl_xor(a2, d);
        }
        if (lane < 3) {
            float v = (lane == 0) ? (a0 + b0) : ((lane == 1) ? (a1 + b1) : (a2 + b2));
            out[row * NT + lane] = fmaxf(v, 0.f);
        }
    }
}

// ---------------------------------------------------------------------------
// Kernel 2: CRF NLL. One 64-lane block per batch. The forward recursion
// alpha_s = alpha_{s-1} (x) M_s in the logsumexp semiring needs only the FINAL
// alpha, so it is an ordered reduction of 3x3 log-matrices: each lane composes
// its 8 step-matrices serially, then a 6-step shfl_down ordered tree combine.
// Masked steps (s >= len) are semiring identities (exact under compose).
// ---------------------------------------------------------------------------
__global__ __launch_bounds__(64) void crf_kernel(
    const float* __restrict__ emis,     // [NB*NS, NT] (relu'd, = d_out)
    const int*   __restrict__ labels,   // [NB, NS]
    const int*   __restrict__ mask,     // [NB, NS] prefix mask
    const float* __restrict__ trans,    // [NT, NT]
    const float* __restrict__ startv,   // [NT]
    const float* __restrict__ endv,     // [NT]
    float* __restrict__ nll)            // &d_out[EMIS_N]
{
    const int b    = blockIdx.x;
    const int lane = threadIdx.x;
    const int*   mrow = mask   + b * NS;
    const int*   lrow = labels + b * NS;
    const float* erow = emis   + (size_t)b * NS * NT;

    // length = sum(mask row), coalesced + shuffle reduce
    int lsum = 0;
    #pragma unroll
    for (int k = 0; k < 8; ++k) lsum += mrow[lane + k * 64];
    #pragma unroll
    for (int d = 32; d; d >>= 1) lsum += __shfl_xor(lsum, d);
    const int len = lsum;   // in [128, 512]

    float t9[9];
    #pragma unroll
    for (int i = 0; i < 9; ++i) t9[i] = trans[i];

    // P = log-semiring identity
    float P[9] = {0.f, NEGINF, NEGINF, NEGINF, 0.f, NEGINF, NEGINF, NEGINF, 0.f};
    float np = 0.f;                       // numerator partial
    const int s0 = 1 + lane * 8;          // this lane's steps: s0 .. s0+7

    #pragma unroll
    for (int k = 0; k < 8; ++k) {
        const int s = s0 + k;
        if (s < len) {                    // step active iff s <= len-1
            const float e0 = erow[s * 3 + 0];
            const float e1 = erow[s * 3 + 1];
            const float e2 = erow[s * 3 + 2];
            const float ej[3] = {e0, e1, e2};
            float Q[9];
            #pragma unroll
            for (int i = 0; i < 3; ++i) {
                #pragma unroll
                for (int j = 0; j < 3; ++j) {
                    Q[i * 3 + j] = lse3(P[i * 3 + 0] + t9[j],
                                        P[i * 3 + 1] + t9[3 + j],
                                        P[i * 3 + 2] + t9[6 + j]) + ej[j];
                }
            }
            #pragma unroll
            for (int i = 0; i < 9; ++i) P[i] = Q[i];

            const int cur = lrow[s], prev = lrow[s - 1];
            np += t9[prev * 3 + cur] + ej[cur];
        }
    }

    // ordered tree combine across lanes (lane l covers steps [1+8l, 1+8l+8))
    #pragma unroll
    for (int d = 1; d < 64; d <<= 1) {
        float Q[9];
        #pragma unroll
        for (int i = 0; i < 9; ++i) Q[i] = __shfl_down(P[i], d);
        const bool valid = (lane + d) < 64;
        float R[9];
        #pragma unroll
        for (int i = 0; i < 3; ++i) {
            #pragma unroll
            for (int j = 0; j < 3; ++j) {
                R[i * 3 + j] = lse3(P[i * 3 + 0] + Q[0 + j],
                                    P[i * 3 + 1] + Q[3 + j],
                                    P[i * 3 + 2] + Q[6 + j]);
            }
        }
        #pragma unroll
        for (int i = 0; i < 9; ++i) P[i] = valid ? R[i] : P[i];
    }

    // numerator reduce
    #pragma unroll
    for (int d = 32; d; d >>= 1) np += __shfl_xor(np, d);

    if (lane == 0) {
        const float a0 = startv[0] + erow[0];
        const float a1 = startv[1] + erow[1];
        const float a2 = startv[2] + erow[2];
        const float f0 = lse3(a0 + P[0], a1 + P[3], a2 + P[6]);
        const float f1 = lse3(a0 + P[1], a1 + P[4], a2 + P[7]);
        const float f2 = lse3(a0 + P[2], a1 + P[5], a2 + P[8]);
        const float logZ = lse3(f0 + endv[0], f1 + endv[1], f2 + endv[2]);

        const int t0 = lrow[0];
        const int tl = lrow[len - 1];
        const float num = np + startv[t0] + erow[t0] + endv[tl];
        atomicAdd(nll, logZ - num);
    }
}

extern "C" void kernel_launch(void* const* d_in, const int* in_sizes, int n_in,
                              void* d_out, int out_size, void* d_ws, size_t ws_size,
                              hipStream_t stream) {
    const float* hidden = (const float*)d_in[0];
    const int*   labels = (const int*)  d_in[1];
    const int*   maskp  = (const int*)  d_in[2];
    const float* W      = (const float*)d_in[3];
    const float* bias   = (const float*)d_in[4];
    const float* trans  = (const float*)d_in[5];
    const float* startv = (const float*)d_in[6];
    const float* endv   = (const float*)d_in[7];
    float* out = (float*)d_out;

    emis_kernel<<<2048, 256, 0, stream>>>(hidden, W, bias, out);
    crf_kernel<<<NB, 64, 0, stream>>>(out, labels, maskp, trans, startv, endv, out + EMIS_N);
}

// Round 2
// 32.858 us; speedup vs baseline: 1.0225x; 1.0225x over previous
//
#include <hip/hip_runtime.h>
#include <math.h>

#define NB 64
#define NS 512
#define NH 768
#define NT 3
#define EMIS_N (NB * NS * NT)   // 98304
#define NEGINF (-1e30f)

__device__ __forceinline__ float lse3(float a, float b, float c) {
    float m = fmaxf(fmaxf(a, b), c);
    return m + __logf(__expf(a - m) + __expf(b - m) + __expf(c - m));
}

// ---------------------------------------------------------------------------
// Kernel 1: emissions = relu(hidden @ W + b).
// 16 lanes per row, 4 rows per wave concurrently. Each lane: 12 independent
// float4 hidden loads (full MLP), W re-read per tile from L1 (9 KB, hot).
// Reduce = 4 shfl_xor stages x 3 accs per wave (vs 6 stages x 3 x 4 rows).
// ---------------------------------------------------------------------------
__global__ __launch_bounds__(256) void emis_kernel(
    const float* __restrict__ hidden,   // [NB*NS, NH]
    const float* __restrict__ W,        // [NH, NT]
    const float* __restrict__ bias,     // [NT]
    float* __restrict__ out)            // d_out: emissions [NB*NS, NT], then nll
{
    if (blockIdx.x == 0 && threadIdx.x == 0) out[EMIS_N] = 0.0f;  // init nll acc

    const int lane = threadIdx.x & 63;
    const int wid  = blockIdx.x * 4 + (threadIdx.x >> 6);   // 0..8191
    const int sub  = lane & 15;        // position within row (h-chunk)
    const int rsel = lane >> 4;        // which of the wave's 4 rows
    const int row  = wid * 4 + rsel;

    const float* hrow = hidden + (size_t)row * NH;

    float a0 = 0.f, a1 = 0.f, a2 = 0.f;
    #pragma unroll
    for (int it = 0; it < 12; ++it) {
        const int h0 = it * 64 + sub * 4;           // 4 h-rows starting here
        const float4 x  = *reinterpret_cast<const float4*>(hrow + h0);
        const float4 q0 = *reinterpret_cast<const float4*>(W + h0 * 3);
        const float4 q1 = *reinterpret_cast<const float4*>(W + h0 * 3 + 4);
        const float4 q2 = *reinterpret_cast<const float4*>(W + h0 * 3 + 8);
        a0 = fmaf(x.x, q0.x, a0); a1 = fmaf(x.x, q0.y, a1); a2 = fmaf(x.x, q0.z, a2);
        a0 = fmaf(x.y, q0.w, a0); a1 = fmaf(x.y, q1.x, a1); a2 = fmaf(x.y, q1.y, a2);
        a0 = fmaf(x.z, q1.z, a0); a1 = fmaf(x.z, q1.w, a1); a2 = fmaf(x.z, q2.x, a2);
        a0 = fmaf(x.w, q2.y, a0); a1 = fmaf(x.w, q2.z, a1); a2 = fmaf(x.w, q2.w, a2);
    }

    // reduce within each 16-lane group (xor masks 8,4,2,1 stay in-group)
    #pragma unroll
    for (int d = 8; d; d >>= 1) {
        a0 += __shfl_xor(a0, d);
        a1 += __shfl_xor(a1, d);
        a2 += __shfl_xor(a2, d);
    }

    if (sub < 3) {
        const float v = (sub == 0) ? (a0 + bias[0])
                      : (sub == 1) ? (a1 + bias[1])
                                   : (a2 + bias[2]);
        out[row * NT + sub] = fmaxf(v, 0.f);   // 12 active lanes -> 48B contiguous
    }
}

// ---------------------------------------------------------------------------
// Kernel 2: CRF NLL. One 64-lane block per batch. Forward recursion as an
// ordered reduction of 3x3 log-semiring matrices: 8 serial composes per lane,
// then a 6-step shfl_down ordered tree. Masked steps are semiring identities.
// ---------------------------------------------------------------------------
__global__ __launch_bounds__(64) void crf_kernel(
    const float* __restrict__ emis,     // [NB*NS, NT] (relu'd, = d_out)
    const int*   __restrict__ labels,   // [NB, NS]
    const int*   __restrict__ mask,     // [NB, NS] prefix mask
    const float* __restrict__ trans,    // [NT, NT]
    const float* __restrict__ startv,   // [NT]
    const float* __restrict__ endv,     // [NT]
    float* __restrict__ nll)            // &d_out[EMIS_N]
{
    const int b    = blockIdx.x;
    const int lane = threadIdx.x;
    const int*   mrow = mask   + b * NS;
    const int*   lrow = labels + b * NS;
    const float* erow = emis   + (size_t)b * NS * NT;

    // length = sum(mask row), coalesced + shuffle reduce
    int lsum = 0;
    #pragma unroll
    for (int k = 0; k < 8; ++k) lsum += mrow[lane + k * 64];
    #pragma unroll
    for (int d = 32; d; d >>= 1) lsum += __shfl_xor(lsum, d);
    const int len = lsum;   // in [128, 512]

    float t9[9];
    #pragma unroll
    for (int i = 0; i < 9; ++i) t9[i] = trans[i];

    const int s0 = 1 + lane * 8;          // this lane's steps: s0 .. s0+7

    // labels this lane touches: s0-1 .. s0+7 (9 loads, reused pairwise)
    int lab[9];
    #pragma unroll
    for (int i = 0; i < 9; ++i) lab[i] = lrow[s0 - 1 + i];

    // P = log-semiring identity
    float P[9] = {0.f, NEGINF, NEGINF, NEGINF, 0.f, NEGINF, NEGINF, NEGINF, 0.f};
    float np = 0.f;                       // numerator partial

    #pragma unroll
    for (int k = 0; k < 8; ++k) {
        const int s = s0 + k;
        if (s < len) {                    // step active iff s <= len-1
            const float e0 = erow[s * 3 + 0];
            const float e1 = erow[s * 3 + 1];
            const float e2 = erow[s * 3 + 2];
            const float ej[3] = {e0, e1, e2};
            float Q[9];
            #pragma unroll
            for (int i = 0; i < 3; ++i) {
                #pragma unroll
                for (int j = 0; j < 3; ++j) {
                    Q[i * 3 + j] = lse3(P[i * 3 + 0] + t9[j],
                                        P[i * 3 + 1] + t9[3 + j],
                                        P[i * 3 + 2] + t9[6 + j]) + ej[j];
                }
            }
            #pragma unroll
            for (int i = 0; i < 9; ++i) P[i] = Q[i];

            np += t9[lab[k] * 3 + lab[k + 1]] + ej[lab[k + 1]];
        }
    }

    // ordered tree combine across lanes (lane l covers steps [1+8l, 1+8l+8))
    #pragma unroll
    for (int d = 1; d < 64; d <<= 1) {
        float Q[9];
        #pragma unroll
        for (int i = 0; i < 9; ++i) Q[i] = __shfl_down(P[i], d);
        const bool valid = (lane + d) < 64;
        float R[9];
        #pragma unroll
        for (int i = 0; i < 3; ++i) {
            #pragma unroll
            for (int j = 0; j < 3; ++j) {
                R[i * 3 + j] = lse3(P[i * 3 + 0] + Q[0 + j],
                                    P[i * 3 + 1] + Q[3 + j],
                                    P[i * 3 + 2] + Q[6 + j]);
            }
        }
        #pragma unroll
        for (int i = 0; i < 9; ++i) P[i] = valid ? R[i] : P[i];
    }

    // numerator reduce
    #pragma unroll
    for (int d = 32; d; d >>= 1) np += __shfl_xor(np, d);

    if (lane == 0) {
        const float a0 = startv[0] + erow[0];
        const float a1 = startv[1] + erow[1];
        const float a2 = startv[2] + erow[2];
        const float f0 = lse3(a0 + P[0], a1 + P[3], a2 + P[6]);
        const float f1 = lse3(a0 + P[1], a1 + P[4], a2 + P[7]);
        const float f2 = lse3(a0 + P[2], a1 + P[5], a2 + P[8]);
        const float logZ = lse3(f0 + endv[0], f1 + endv[1], f2 + endv[2]);

        const int t0 = lrow[0];
        const int tl = lrow[len - 1];
        const float num = np + startv[t0] + erow[t0] + endv[tl];
        atomicAdd(nll, logZ - num);
    }
}

extern "C" void kernel_launch(void* const* d_in, const int* in_sizes, int n_in,
                              void* d_out, int out_size, void* d_ws, size_t ws_size,
                              hipStream_t stream) {
    const float* hidden = (const float*)d_in[0];
    const int*   labels = (const int*)  d_in[1];
    const int*   maskp  = (const int*)  d_in[2];
    const float* W      = (const float*)d_in[3];
    const float* bias   = (const float*)d_in[4];
    const float* trans  = (const float*)d_in[5];
    const float* startv = (const float*)d_in[6];
    const float* endv   = (const float*)d_in[7];
    float* out = (float*)d_out;

    emis_kernel<<<2048, 256, 0, stream>>>(hidden, W, bias, out);
    crf_kernel<<<NB, 64, 0, stream>>>(out, labels, maskp, trans, startv, endv, out + EMIS_N);
}

// Round 3
// 28.864 us; speedup vs baseline: 1.1640x; 1.1384x over previous
//
#include <hip/hip_runtime.h>
#include <math.h>

#define NB 64
#define NS 512
#define NH 768
#define NT 3
#define EMIS_N (NB * NS * NT)   // 98304
#define NEGINF (-1e30f)
#define WPB 128                 // waves per batch in kernel 1 (512 rows / 4)
#define PSTRIDE 12              // floats per wave partial in ws (9 mat + 1 num, padded)

__device__ __forceinline__ float lse3(float a, float b, float c) {
    float m = fmaxf(fmaxf(a, b), c);
    return m + __logf(__expf(a - m) + __expf(b - m) + __expf(c - m));
}

// ---------------------------------------------------------------------------
// Kernel 1: emissions = relu(hidden @ W + b) FUSED with per-wave CRF partial.
// 16 lanes per row, 4 consecutive rows (one batch) per wave. After the GEMV
// reduce, every lane holds its group's 3 emissions; the wave composes its 4
// step matrices (log-semiring, 9 lanes parallel) and its numerator partial,
// writing a 10-float partial to ws. Compose cost hides under HBM streaming.
// ---------------------------------------------------------------------------
__global__ __launch_bounds__(256) void emis_crf_kernel(
    const float* __restrict__ hidden,   // [NB*NS, NH]
    const int*   __restrict__ labels,   // [NB, NS]
    const int*   __restrict__ mask,     // [NB, NS]
    const float* __restrict__ W,        // [NH, NT]
    const float* __restrict__ bias,     // [NT]
    const float* __restrict__ trans,    // [NT, NT]
    const float* __restrict__ startv,   // [NT]
    float* __restrict__ out,            // emissions [NB*NS, NT], then nll
    float* __restrict__ ws)             // [8192 waves][PSTRIDE]
{
    if (blockIdx.x == 0 && threadIdx.x == 0) out[EMIS_N] = 0.0f;  // init nll acc

    const int lane = threadIdx.x & 63;
    const int wid  = blockIdx.x * 4 + (threadIdx.x >> 6);   // 0..8191
    const int sub  = lane & 15;        // h-chunk within row
    const int rsel = lane >> 4;        // which of the wave's 4 rows
    const int row  = wid * 4 + rsel;
    const int b    = wid >> 7;         // batch (128 waves per batch)
    const int w    = wid & 127;        // wave index within batch
    const int p    = (w << 2) + rsel;  // sequence position of this group's row

    const float* hrow = hidden + (size_t)row * NH;

    float a0 = 0.f, a1 = 0.f, a2 = 0.f;
    #pragma unroll
    for (int it = 0; it < 12; ++it) {
        const int h0 = it * 64 + sub * 4;
        const float4 x  = *reinterpret_cast<const float4*>(hrow + h0);
        const float4 q0 = *reinterpret_cast<const float4*>(W + h0 * 3);
        const float4 q1 = *reinterpret_cast<const float4*>(W + h0 * 3 + 4);
        const float4 q2 = *reinterpret_cast<const float4*>(W + h0 * 3 + 8);
        a0 = fmaf(x.x, q0.x, a0); a1 = fmaf(x.x, q0.y, a1); a2 = fmaf(x.x, q0.z, a2);
        a0 = fmaf(x.y, q0.w, a0); a1 = fmaf(x.y, q1.x, a1); a2 = fmaf(x.y, q1.y, a2);
        a0 = fmaf(x.z, q1.z, a0); a1 = fmaf(x.z, q1.w, a1); a2 = fmaf(x.z, q2.x, a2);
        a0 = fmaf(x.w, q2.y, a0); a1 = fmaf(x.w, q2.z, a1); a2 = fmaf(x.w, q2.w, a2);
    }
    #pragma unroll
    for (int d = 8; d; d >>= 1) {
        a0 += __shfl_xor(a0, d);
        a1 += __shfl_xor(a1, d);
        a2 += __shfl_xor(a2, d);
    }

    // all 16 lanes of each group now hold the row's 3 pre-activations
    const float e0 = fmaxf(a0 + bias[0], 0.f);
    const float e1 = fmaxf(a1 + bias[1], 0.f);
    const float e2 = fmaxf(a2 + bias[2], 0.f);

    if (sub < 3) out[row * NT + sub] = (sub == 0) ? e0 : (sub == 1) ? e1 : e2;

    // ---- CRF partial: per-group metadata on sub==0 lanes ----
    const int* lrow = labels + b * NS;
    const int* mrow = mask   + b * NS;
    int   mk = 0;
    float term = 0.f;   // numerator contribution of this group's step
    if (sub == 0) {
        mk = mrow[p];
        const int labc = lrow[p];
        const float esel = (labc == 0) ? e0 : (labc == 1) ? e1 : e2;
        if (p == 0) {
            term = startv[labc] + esel;               // boundary: start + e0 term
        } else if (mk) {
            const int labp = lrow[p - 1];
            term = trans[labp * 3 + labc] + esel;     // step term
        }
    }

    // ---- compose 4 step matrices (9 active lanes, lane = i*3+j) ----
    const int il = (lane < 9) ? (lane / 3) : 0;
    const int jl = (lane < 9) ? (lane % 3) : 0;
    const float tc0 = trans[jl], tc1 = trans[3 + jl], tc2 = trans[6 + jl];
    float Pv = (il == jl) ? 0.f : NEGINF;             // log-semiring identity

    #pragma unroll
    for (int k = 0; k < 4; ++k) {
        const int src = k << 4;
        const float ee0 = __shfl(e0, src);
        const float ee1 = __shfl(e1, src);
        const float ee2 = __shfl(e2, src);
        const int   mm  = __shfl(mk, src);
        const float Pi0 = __shfl(Pv, il * 3 + 0);
        const float Pi1 = __shfl(Pv, il * 3 + 1);
        const float Pi2 = __shfl(Pv, il * 3 + 2);
        const float ej  = (jl == 0) ? ee0 : (jl == 1) ? ee1 : ee2;
        const float q   = lse3(Pi0 + tc0, Pi1 + tc1, Pi2 + tc2) + ej;
        const bool act  = (((w << 2) + k) >= 1) && (mm != 0);
        Pv = act ? q : Pv;
    }

    // numerator partial of the wave (groups' terms live at lanes 0,16,32,48)
    const float np = __shfl(term, 0) + __shfl(term, 16) +
                     __shfl(term, 32) + __shfl(term, 48);

    float* wp = ws + wid * PSTRIDE;
    if (lane < 9) wp[lane] = Pv;
    if (lane == 0) wp[9] = np;
}

// ---------------------------------------------------------------------------
// Kernel 2: combiner. One 64-lane block per batch: each lane folds 2 wave
// partials (positions [8l, 8l+8)), then a 6-step ordered shfl_down tree,
// then boundary terms -> atomicAdd(nll).
// ---------------------------------------------------------------------------
__global__ __launch_bounds__(64) void crf_combine(
    const float* __restrict__ emis,     // [NB*NS, NT] (= d_out)
    const int*   __restrict__ labels,   // [NB, NS]
    const int*   __restrict__ mask,     // [NB, NS]
    const float* __restrict__ startv,   // [NT]
    const float* __restrict__ endv,     // [NT]
    const float* __restrict__ ws,       // wave partials
    float* __restrict__ nll)            // &d_out[EMIS_N]
{
    const int b    = blockIdx.x;
    const int lane = threadIdx.x;
    const int* mrow = mask   + b * NS;
    const int* lrow = labels + b * NS;

    int lsum = 0;
    #pragma unroll
    for (int k = 0; k < 8; ++k) lsum += mrow[lane + k * 64];
    #pragma unroll
    for (int d = 32; d; d >>= 1) lsum += __shfl_xor(lsum, d);
    const int len = lsum;

    const float* base = ws + (size_t)b * WPB * PSTRIDE;
    const float* pa = base + (2 * lane)     * PSTRIDE;
    const float* pb = base + (2 * lane + 1) * PSTRIDE;
    float A[9], Bm[9];
    #pragma unroll
    for (int i = 0; i < 9; ++i) A[i]  = pa[i];
    #pragma unroll
    for (int i = 0; i < 9; ++i) Bm[i] = pb[i];
    float np = pa[9] + pb[9];

    float P[9];
    #pragma unroll
    for (int i = 0; i < 3; ++i)
        #pragma unroll
        for (int j = 0; j < 3; ++j)
            P[i * 3 + j] = lse3(A[i * 3 + 0] + Bm[0 + j],
                                A[i * 3 + 1] + Bm[3 + j],
                                A[i * 3 + 2] + Bm[6 + j]);

    // ordered tree combine (lane l covers positions [8l, 8l+8))
    #pragma unroll
    for (int d = 1; d < 64; d <<= 1) {
        float Q[9];
        #pragma unroll
        for (int i = 0; i < 9; ++i) Q[i] = __shfl_down(P[i], d);
        const bool valid = (lane + d) < 64;
        float R[9];
        #pragma unroll
        for (int i = 0; i < 3; ++i)
            #pragma unroll
            for (int j = 0; j < 3; ++j)
                R[i * 3 + j] = lse3(P[i * 3 + 0] + Q[0 + j],
                                    P[i * 3 + 1] + Q[3 + j],
                                    P[i * 3 + 2] + Q[6 + j]);
        #pragma unroll
        for (int i = 0; i < 9; ++i) P[i] = valid ? R[i] : P[i];
    }

    #pragma unroll
    for (int d = 32; d; d >>= 1) np += __shfl_xor(np, d);

    if (lane == 0) {
        const float* erow = emis + (size_t)b * NS * NT;
        const float a0 = startv[0] + erow[0];
        const float a1 = startv[1] + erow[1];
        const float a2 = startv[2] + erow[2];
        const float f0 = lse3(a0 + P[0], a1 + P[3], a2 + P[6]);
        const float f1 = lse3(a0 + P[1], a1 + P[4], a2 + P[7]);
        const float f2 = lse3(a0 + P[2], a1 + P[5], a2 + P[8]);
        const float logZ = lse3(f0 + endv[0], f1 + endv[1], f2 + endv[2]);

        const int tl = lrow[len - 1];
        const float num = np + endv[tl];   // start + e0 term already in np
        atomicAdd(nll, logZ - num);
    }
}

extern "C" void kernel_launch(void* const* d_in, const int* in_sizes, int n_in,
                              void* d_out, int out_size, void* d_ws, size_t ws_size,
                              hipStream_t stream) {
    const float* hidden = (const float*)d_in[0];
    const int*   labels = (const int*)  d_in[1];
    const int*   maskp  = (const int*)  d_in[2];
    const float* W      = (const float*)d_in[3];
    const float* bias   = (const float*)d_in[4];
    const float* trans  = (const float*)d_in[5];
    const float* startv = (const float*)d_in[6];
    const float* endv   = (const float*)d_in[7];
    float* out = (float*)d_out;
    float* ws  = (float*)d_ws;   // needs 8192 * 12 * 4 B = 384 KB

    emis_crf_kernel<<<2048, 256, 0, stream>>>(hidden, labels, maskp, W, bias,
                                              trans, startv, out, ws);
    crf_combine<<<NB, 64, 0, stream>>>(out, labels, maskp, startv, endv, ws,
                                       out + EMIS_N);
}